// Round 6
// baseline (393.463 us; speedup 1.0000x reference)
//
#include <hip/hip_runtime.h>

typedef _Float16 half8 __attribute__((ext_vector_type(8)));
typedef _Float16 half4v __attribute__((ext_vector_type(4)));
typedef float floatx4 __attribute__((ext_vector_type(4)));

#define C_DIM 256
#define M_DIM 512
#define HW 4096
#define TAU 0.0025f
#define LCAP 16

// Raw barrier: LDS-visibility only (skip the implicit vmcnt(0) drain of
// __syncthreads). Used where the post-barrier phase reads ONLY LDS, so
// in-flight global ops keep draining underneath (HK T4 pattern).
// sched_barrier(0) stops hipcc hoisting post-barrier ops above it (rule #18).
#define BAR_LGKM()                                          \
  do {                                                      \
    asm volatile("s_waitcnt lgkmcnt(0)" ::: "memory");      \
    __builtin_amdgcn_s_barrier();                           \
    __builtin_amdgcn_sched_barrier(0);                      \
  } while (0)

// ---------------- zero: contiguous NT zero-fill of out+attmap (201 MB) -------------
// att (and hence out) is ~99.99% zero; write all zeros contiguously at stream BW
// (~31 us) and let main scatter only survivors. 3072 x 256 x 16 float4 = 201.3 MB.
__global__ __launch_bounds__(256) void zero_kernel(float* __restrict__ base)
{
  const floatx4 z = {0.f, 0.f, 0.f, 0.f};
  floatx4* p = (floatx4*)base + (size_t)blockIdx.x * 256 + threadIdx.x;
#pragma unroll
  for (int k = 0; k < 16; ++k)
    __builtin_nontemporal_store(z, p + (size_t)k * 786432);  // 3072*256 stride
}

// ---------------- prep: memN = l2norm(relu(relu(mem@w1+b1)@w2+b2)) ----------------
// MLP only; bit-identical reduction order vs original.
__global__ __launch_bounds__(128) void prep_kernel(
    const float* __restrict__ memory, const float* __restrict__ w1,
    const float* __restrict__ b1, const float* __restrict__ w2,
    const float* __restrict__ b2,
    _Float16* __restrict__ mN, float* __restrict__ mN32)
{
  __shared__ float sm[256];
  __shared__ float sh[128];
  __shared__ float s_part[2];
  __shared__ float s_tot;
  const int r = blockIdx.x;   // 0..511
  const int t = threadIdx.x;  // 0..127

  sm[t]       = memory[r * C_DIM + t];
  sm[t + 128] = memory[r * C_DIM + t + 128];
  __syncthreads();
  float acc = b1[t];
#pragma unroll 8
  for (int c = 0; c < 256; ++c) acc = fmaf(sm[c], w1[c * 128 + t], acc);
  sh[t] = fmaxf(acc, 0.f);
  __syncthreads();
  float o0 = b2[t], o1 = b2[t + 128];
#pragma unroll 8
  for (int k = 0; k < 128; ++k) {
    float h = sh[k];
    o0 = fmaf(h, w2[k * 256 + t], o0);
    o1 = fmaf(h, w2[k * 256 + t + 128], o1);
  }
  o0 = fmaxf(o0, 0.f);
  o1 = fmaxf(o1, 0.f);
  float ss = o0 * o0 + o1 * o1;
#pragma unroll
  for (int off = 32; off >= 1; off >>= 1) ss += __shfl_down(ss, off);
  if ((t & 63) == 0) s_part[t >> 6] = ss;
  __syncthreads();
  if (t == 0) s_tot = s_part[0] + s_part[1];
  __syncthreads();
  const float inv = 1.f / fmaxf(sqrtf(s_tot), 1e-12f);
  const float v0 = o0 * inv, v1 = o1 * inv;
  mN[r * C_DIM + t]        = (_Float16)v0;
  mN[r * C_DIM + t + 128]  = (_Float16)v1;
  mN32[r * C_DIM + t]       = v0;
  mN32[r * C_DIM + t + 128] = v1;
}

#define MFMA16(a, b, c) __builtin_amdgcn_mfma_f32_16x16x32_f16(a, b, c, 0, 0, 0)

// -------- fused main kernel: 2 tiles x 32 px per block, 1024 blocks ----------------
// R16: tile-size series {64px:129us, 32px:~107, 16px:141} shows duration is set by
// per-block FIXED latency (barrier chain + exposed Phase-A x-load round-trip), not
// TLP (R15: 83% occupancy, every pipe <22%, x stream at only 485 GB/s because loads
// issue only in each block's short Phase-A window). Fix: 32-px tile (best measured),
// TWO tiles per block, tile-1 x-loads issued right after B0 of tile 0 -> they drain
// under tile-0's whole GEMM+softmax+epilogue (T14 issue-early/consume-late). Halves
// block count (halves fixed cost), hides the load latency for every 2nd tile.
// Per-output arithmetic/reduction order byte-identical to the verified 32-px path.
__global__ __launch_bounds__(512, 6) void main_kernel(
    const float* __restrict__ x,
    const _Float16* __restrict__ mN,
    const float* __restrict__ mN32,
    float* __restrict__ out, float* __restrict__ attmap)
{
  __shared__ _Float16       Xh[32][264];       // 16896 B
  __shared__ unsigned short s_lslot[32][LCAP]; // 1024 B
  __shared__ float          s_lval[32][LCAP];  // 2048 B
  __shared__ int      s_cnt[32];
  __shared__ float    s_sumsq[32];
  __shared__ float    s_sum1[32];
  __shared__ float    s_sum2[32];               // total 20480 B

  const int tid  = threadIdx.x;
  const int wave = tid >> 6;     // 0..7
  const int lane = tid & 63;
  const int q    = lane >> 4;    // quad within wave
  const int c16  = lane & 15;
  const int g    = tid >> 3;     // 0..63: channel quad for phase A
  const int pxq  = tid & 7;      // pixel quad for phase A

  const int blk  = blockIdx.x;         // 1024 blocks
  const int img  = blk >> 6;           // 64 blocks (= 2-tile pairs) per image
  const int hw00 = (blk & 63) * 64;    // tile 0 at hw00, tile 1 at hw00+32
  const float* __restrict__ xb = x + (size_t)img * C_DIM * HW + hw00;

  // issue x loads: 4 float4 per thread (4 ch x 4 px), register-resident
  auto issueLoads = [&](floatx4 (&v)[4], int hoff) {
#pragma unroll
    for (int i = 0; i < 4; ++i)
      v[i] = *(const floatx4*)(xb + (size_t)(4 * g + i) * HW + hoff + pxq * 4);
  };

  // pack to fp16 LDS + per-pixel sumsq (identical geometry to verified 32-px path)
  auto phaseA = [&](const floatx4 (&v)[4]) {
    float ps[4];
#pragma unroll
    for (int j = 0; j < 4; ++j) {
      const int p = pxq * 4 + j;
      half4v hv = {(_Float16)v[0][j], (_Float16)v[1][j], (_Float16)v[2][j], (_Float16)v[3][j]};
      *(half4v*)&Xh[p][4 * g] = hv;
      ps[j] = v[0][j] * v[0][j] + v[1][j] * v[1][j] + v[2][j] * v[2][j] + v[3][j] * v[3][j];
    }
#pragma unroll
    for (int off = 8; off < 64; off <<= 1)
#pragma unroll
      for (int j = 0; j < 4; ++j) ps[j] += __shfl_xor(ps[j], off);
    if ((lane >> 3) == 0) {
#pragma unroll
      for (int j = 0; j < 4; ++j) atomicAdd(&s_sumsq[4 * (lane & 7) + j], ps[j]);
    }
  };

  // B base pointers — tile-invariant, computed once (kb offsets fold into imm)
  const _Float16* bp[4];
#pragma unroll
  for (int nt = 0; nt < 4; ++nt)
    bp[nt] = mN + (size_t)(wave * 64 + nt * 16 + c16) * C_DIM + q * 8;

  // GEMM -> softmax -> shrink -> scatter -> gather for one packed 32-px tile
  auto processTile = [&](int hw0) {
    // ---- Phase B: GEMM1  S[32][512] = Xh @ mN^T  (fp16 MFMA)
    floatx4 acc[2][4];
#pragma unroll
    for (int mt = 0; mt < 2; ++mt)
#pragma unroll
      for (int nt = 0; nt < 4; ++nt) {
        floatx4 z = {0.f, 0.f, 0.f, 0.f};
        acc[mt][nt] = z;
      }
#pragma unroll
    for (int kb = 0; kb < 8; ++kb) {
      half8 bv[4];
#pragma unroll
      for (int nt = 0; nt < 4; ++nt) bv[nt] = *(const half8*)(bp[nt] + kb * 32);
      const int k0 = kb * 32 + q * 8;
      half8 a0 = *(const half8*)&Xh[c16][k0];
      half8 a1 = *(const half8*)&Xh[16 + c16][k0];
#pragma unroll
      for (int nt = 0; nt < 4; ++nt) {
        acc[0][nt] = MFMA16(a0, bv[nt], acc[0][nt]);
        acc[1][nt] = MFMA16(a1, bv[nt], acc[1][nt]);
      }
    }

    // ---- Phase C: scale by 1/||x||, exp; C/D: (m = mt*16+q*4+r, n = wave*64+nt*16+c16)
#pragma unroll
    for (int mt = 0; mt < 2; ++mt)
#pragma unroll
      for (int r = 0; r < 4; ++r) {
        const int m = mt * 16 + q * 4 + r;
        const float iv = 1.f / fmaxf(sqrtf(s_sumsq[m]), 1e-12f);
        float s = 0.f;
#pragma unroll
        for (int nt = 0; nt < 4; ++nt) {
          const float e = __expf(acc[mt][nt][r] * iv);
          acc[mt][nt][r] = e;
          s += e;
        }
        s += __shfl_xor(s, 1);
        s += __shfl_xor(s, 2);
        s += __shfl_xor(s, 4);
        s += __shfl_xor(s, 8);
        if (c16 == 0) atomicAdd(&s_sum1[m], s);
      }
    __syncthreads();  // B2: softmax denominators ready

    // t = relu(p - tau); row sum of t
#pragma unroll
    for (int mt = 0; mt < 2; ++mt)
#pragma unroll
      for (int r = 0; r < 4; ++r) {
        const int m = mt * 16 + q * 4 + r;
        const float isum = 1.f / s_sum1[m];
        float s = 0.f;
#pragma unroll
        for (int nt = 0; nt < 4; ++nt) {
          const float tv = fmaxf(acc[mt][nt][r] * isum - TAU, 0.f);
          acc[mt][nt][r] = tv;
          s += tv;
        }
        s += __shfl_xor(s, 1);
        s += __shfl_xor(s, 2);
        s += __shfl_xor(s, 4);
        s += __shfl_xor(s, 8);
        if (c16 == 0) atomicAdd(&s_sum2[m], s);
      }
    __syncthreads();  // B3: shrink sums ready

    // ---- normalize; rare survivors -> LDS lists + scalar scatter to attmap
#pragma unroll
    for (int mt = 0; mt < 2; ++mt) {
      float rs[4];
#pragma unroll
      for (int r = 0; r < 4; ++r)
        rs[r] = 1.f / fmaxf(s_sum2[mt * 16 + q * 4 + r], 1e-12f);
#pragma unroll
      for (int nt = 0; nt < 4; ++nt) {
        floatx4 a4 = acc[mt][nt];
        const unsigned n = wave * 64 + nt * 16 + c16;
#pragma unroll
        for (int r = 0; r < 4; ++r) {
          a4[r] *= rs[r];
          if (a4[r] > 0.f) {
            const int m = mt * 16 + q * 4 + r;
            const int idx = atomicAdd(&s_cnt[m], 1);
            if (idx < LCAP) {
              s_lslot[m][idx] = (unsigned short)n;
              s_lval[m][idx]  = a4[r];
            }
            attmap[((size_t)img * M_DIM + n) * HW + hw0 + m] = a4[r];
          }
        }
      }
    }
    BAR_LGKM();  // B4: lists ready — LDS-only sync; global stores keep draining

    // ---- sparse gather, predicated: only pixel groups with survivors do work
    const int px4 = (tid & 7) * 4;    // pixels px4..px4+3
    const int chg = tid >> 3;         // 0..63 -> channels [4*chg, 4*chg+4)
    int cn[4];
    int any = 0;
#pragma unroll
    for (int p = 0; p < 4; ++p) { cn[p] = min(s_cnt[px4 + p], LCAP); any += cn[p]; }
    if (any) {
      floatx4 f[4] = {{0.f,0.f,0.f,0.f},{0.f,0.f,0.f,0.f},{0.f,0.f,0.f,0.f},{0.f,0.f,0.f,0.f}};
#pragma unroll
      for (int p = 0; p < 4; ++p) {
        for (int j = 0; j < cn[p]; ++j) {
          const int slot  = s_lslot[px4 + p][j];
          const float v   = s_lval[px4 + p][j];
          const floatx4 r0 = *(const floatx4*)(mN32 + (size_t)slot * C_DIM + chg * 4);
          f[0][p] += v * r0[0]; f[1][p] += v * r0[1];
          f[2][p] += v * r0[2]; f[3][p] += v * r0[3];
        }
      }
#pragma unroll
      for (int c = 0; c < 4; ++c)
        *(floatx4*)(out + ((size_t)img * C_DIM + chg * 4 + c) * HW + hw0 + px4) = f[c];
    }
  };

  floatx4 va[4], vb[4];
  issueLoads(va, 0);                 // tile-0 loads in flight

  // ================= tile 0 =================
  if (tid < 32) {
    s_sumsq[tid] = 0.f; s_sum1[tid] = 0.f; s_sum2[tid] = 0.f; s_cnt[tid] = 0;
  }
  __syncthreads();                   // B0
  issueLoads(vb, 32);                // tile-1 prefetch: drains under tile-0 compute
  phaseA(va);
  __syncthreads();                   // B1: Xh + sumsq ready
  processTile(hw00);

  // ================= tile 1 =================
  BAR_LGKM();                        // gather readers done with LDS lists
  if (tid < 32) {
    s_sumsq[tid] = 0.f; s_sum1[tid] = 0.f; s_sum2[tid] = 0.f; s_cnt[tid] = 0;
  }
  __syncthreads();                   // B0'
  phaseA(vb);
  __syncthreads();                   // B1'
  processTile(hw00 + 32);
}

extern "C" void kernel_launch(void* const* d_in, const int* in_sizes, int n_in,
                              void* d_out, int out_size, void* d_ws, size_t ws_size,
                              hipStream_t stream) {
  (void)in_sizes; (void)n_in; (void)out_size; (void)ws_size;
  const float* x      = (const float*)d_in[0];
  const float* memory = (const float*)d_in[1];
  const float* w1     = (const float*)d_in[2];
  const float* b1     = (const float*)d_in[3];
  const float* w2     = (const float*)d_in[4];
  const float* b2     = (const float*)d_in[5];
  float* out    = (float*)d_out;
  float* attmap = out + (size_t)16 * C_DIM * HW;  // output first, att_map second

  _Float16* mN   = (_Float16*)d_ws;
  float*    mN32 = (float*)((char*)d_ws + (size_t)M_DIM * C_DIM * sizeof(_Float16));

  hipLaunchKernelGGL(zero_kernel, dim3(3072), dim3(256), 0, stream, out);
  hipLaunchKernelGGL(prep_kernel, dim3(M_DIM), dim3(128), 0, stream,
                     memory, w1, b1, w2, b2, mN, mN32);
  hipLaunchKernelGGL(main_kernel, dim3(1024), dim3(512), 0, stream,
                     x, mN, mN32, out, attmap);
}

// Round 7
// 350.630 us; speedup vs baseline: 1.1222x; 1.1222x over previous
//
#include <hip/hip_runtime.h>

typedef _Float16 half8 __attribute__((ext_vector_type(8)));
typedef _Float16 half4v __attribute__((ext_vector_type(4)));
typedef float floatx4 __attribute__((ext_vector_type(4)));

#define C_DIM 256
#define M_DIM 512
#define HW 4096
#define TAU 0.0025f
#define LCAP 16

// Raw barrier: LDS-visibility only (skip the implicit vmcnt(0) drain of
// __syncthreads). Used where the post-barrier phase reads ONLY LDS, so
// in-flight global stores keep draining underneath (HK T4 pattern).
// sched_barrier(0) stops hipcc hoisting post-barrier ops above it (rule #18).
#define BAR_LGKM()                                          \
  do {                                                      \
    asm volatile("s_waitcnt lgkmcnt(0)" ::: "memory");      \
    __builtin_amdgcn_s_barrier();                           \
    __builtin_amdgcn_sched_barrier(0);                      \
  } while (0)

// ---------------- prep: fill(out+attmap) + memN MLP, fused (R0 structure) ----------
// R17: back to the 2-launch structure (every extra launch cost ~10-30 us of
// unmodeled gap in rounds 1-6). Fill extended 134->201.3 MB to pre-zero BOTH out
// and att_map (192 NT float4/thread x 65536 threads), so main can stay fully
// sparse. memory[] loads hoisted above the fill so their HBM latency hides under
// store issue. MLP arithmetic/reduction order bit-identical to the original
// (preserves absmax==0.0).
__global__ __launch_bounds__(128) void prep_kernel(
    const float* __restrict__ memory, const float* __restrict__ w1,
    const float* __restrict__ b1, const float* __restrict__ w2,
    const float* __restrict__ b2,
    _Float16* __restrict__ mN, float* __restrict__ mN32,
    float* __restrict__ outbase)
{
  __shared__ float sm[256];
  __shared__ float sh[128];
  __shared__ float s_part[2];
  __shared__ float s_tot;
  const int r = blockIdx.x;   // 0..511
  const int t = threadIdx.x;  // 0..127

  // hoist MLP input loads: in flight during the fill below
  const float m0 = memory[r * C_DIM + t];
  const float m1 = memory[r * C_DIM + t + 128];
  const float bb1 = b1[t];

  // ---- out+attmap zero-fill: 512 blocks x 128 thr x 192 float4 = 201.3 MB, NT
  {
    const floatx4 z = {0.f, 0.f, 0.f, 0.f};
    floatx4* p4 = (floatx4*)outbase + (size_t)r * 128 + t;  // 65536 threads
#pragma unroll 8
    for (int k = 0; k < 192; ++k)
      __builtin_nontemporal_store(z, p4 + (size_t)k * 65536);
  }

  sm[t]       = m0;
  sm[t + 128] = m1;
  __syncthreads();
  float acc = bb1;
#pragma unroll 8
  for (int c = 0; c < 256; ++c) acc = fmaf(sm[c], w1[c * 128 + t], acc);
  sh[t] = fmaxf(acc, 0.f);
  __syncthreads();
  float o0 = b2[t], o1 = b2[t + 128];
#pragma unroll 8
  for (int k = 0; k < 128; ++k) {
    float h = sh[k];
    o0 = fmaf(h, w2[k * 256 + t], o0);
    o1 = fmaf(h, w2[k * 256 + t + 128], o1);
  }
  o0 = fmaxf(o0, 0.f);
  o1 = fmaxf(o1, 0.f);
  float ss = o0 * o0 + o1 * o1;
#pragma unroll
  for (int off = 32; off >= 1; off >>= 1) ss += __shfl_down(ss, off);
  if ((t & 63) == 0) s_part[t >> 6] = ss;
  __syncthreads();
  if (t == 0) s_tot = s_part[0] + s_part[1];
  __syncthreads();
  const float inv = 1.f / fmaxf(sqrtf(s_tot), 1e-12f);
  const float v0 = o0 * inv, v1 = o1 * inv;
  mN[r * C_DIM + t]        = (_Float16)v0;
  mN[r * C_DIM + t + 128]  = (_Float16)v1;
  mN32[r * C_DIM + t]       = v0;
  mN32[r * C_DIM + t + 128] = v1;
}

#define MFMA16(a, b, c) __builtin_amdgcn_mfma_f32_16x16x32_f16(a, b, c, 0, 0, 0)

// ---------------- fused main kernel: 32 pixels per block, 2048 blocks ----------------
// R4/R14 main VERBATIM — the best-measured main (~107 us): 32-px tile, acc[2][4] =
// 32 AGPR, 20.5 KB LDS, 3 blocks/CU; outputs pre-zeroed in prep -> main scatters
// ONLY survivors (a4[r] > 0, ~1e-5 density) and the gather/out-store phase is
// predicated on per-pixel survivor counts (most blocks store nothing).
// R6 lesson baked in: NO cross-tile register prefetch (it spilled: 108 MB scratch).
__global__ __launch_bounds__(512, 6) void main_kernel(
    const float* __restrict__ x,
    const _Float16* __restrict__ mN,
    const float* __restrict__ mN32,
    float* __restrict__ out, float* __restrict__ attmap)
{
  __shared__ _Float16       Xh[32][264];       // 16896 B
  __shared__ unsigned short s_lslot[32][LCAP]; // 1024 B
  __shared__ float          s_lval[32][LCAP];  // 2048 B
  __shared__ int      s_cnt[32];
  __shared__ float    s_sumsq[32];
  __shared__ float    s_sum1[32];
  __shared__ float    s_sum2[32];               // total 20480 B

  const int tid  = threadIdx.x;
  const int wave = tid >> 6;     // 0..7
  const int lane = tid & 63;
  const int q    = lane >> 4;    // quad within wave
  const int c16  = lane & 15;
  const int g    = tid >> 3;     // 0..63: channel quad for phase A
  const int pxq  = tid & 7;      // pixel quad for phase A

  const int blk = blockIdx.x;          // 2048 blocks
  const int img = blk >> 7;            // 128 blocks per image
  const int hw0 = (blk & 127) * 32;
  const float* __restrict__ xb = x + (size_t)img * C_DIM * HW + hw0;

  if (tid < 32) {
    s_sumsq[tid] = 0.f; s_sum1[tid] = 0.f; s_sum2[tid] = 0.f; s_cnt[tid] = 0;
  }
  __syncthreads();  // B0

  // ---- Phase A: float4 loads (4 ch x 4 px per thread), fp16 pack, sumsq
  {
    floatx4 v[4];
#pragma unroll
    for (int i = 0; i < 4; ++i)
      v[i] = *(const floatx4*)(xb + (size_t)(4 * g + i) * HW + pxq * 4);
    float ps[4];
#pragma unroll
    for (int j = 0; j < 4; ++j) {
      const int p = pxq * 4 + j;
      half4v hv = {(_Float16)v[0][j], (_Float16)v[1][j], (_Float16)v[2][j], (_Float16)v[3][j]};
      *(half4v*)&Xh[p][4 * g] = hv;
      ps[j] = v[0][j] * v[0][j] + v[1][j] * v[1][j] + v[2][j] * v[2][j] + v[3][j] * v[3][j];
    }
#pragma unroll
    for (int off = 8; off < 64; off <<= 1)
#pragma unroll
      for (int j = 0; j < 4; ++j) ps[j] += __shfl_xor(ps[j], off);
    if ((lane >> 3) == 0) {
#pragma unroll
      for (int j = 0; j < 4; ++j) atomicAdd(&s_sumsq[4 * (lane & 7) + j], ps[j]);
    }
  }

  // B base pointers (kb offsets fold into the 13-bit imm: kb*32 halves = 64..448 B)
  const _Float16* bp[4];
#pragma unroll
  for (int nt = 0; nt < 4; ++nt)
    bp[nt] = mN + (size_t)(wave * 64 + nt * 16 + c16) * C_DIM + q * 8;

  __syncthreads();  // B1: Xh + sumsq ready

  // ---- Phase B: GEMM1  S[32][512] = Xh @ mN^T  (fp16 MFMA)
  floatx4 acc[2][4];
#pragma unroll
  for (int mt = 0; mt < 2; ++mt)
#pragma unroll
    for (int nt = 0; nt < 4; ++nt) {
      floatx4 z = {0.f, 0.f, 0.f, 0.f};
      acc[mt][nt] = z;
    }
#pragma unroll
  for (int kb = 0; kb < 8; ++kb) {
    half8 bv[4];
#pragma unroll
    for (int nt = 0; nt < 4; ++nt) bv[nt] = *(const half8*)(bp[nt] + kb * 32);
    const int k0 = kb * 32 + q * 8;
    half8 a0 = *(const half8*)&Xh[c16][k0];
    half8 a1 = *(const half8*)&Xh[16 + c16][k0];
#pragma unroll
    for (int nt = 0; nt < 4; ++nt) {
      acc[0][nt] = MFMA16(a0, bv[nt], acc[0][nt]);
      acc[1][nt] = MFMA16(a1, bv[nt], acc[1][nt]);
    }
  }

  // ---- Phase C: scale by 1/||x||, exp (cosines in [-1,1], no max shift needed)
  // C/D layout: value (m = mt*16 + q*4 + r, n = wave*64 + nt*16 + c16)
#pragma unroll
  for (int mt = 0; mt < 2; ++mt)
#pragma unroll
    for (int r = 0; r < 4; ++r) {
      const int m = mt * 16 + q * 4 + r;
      const float iv = 1.f / fmaxf(sqrtf(s_sumsq[m]), 1e-12f);
      float s = 0.f;
#pragma unroll
      for (int nt = 0; nt < 4; ++nt) {
        const float e = __expf(acc[mt][nt][r] * iv);
        acc[mt][nt][r] = e;
        s += e;
      }
      s += __shfl_xor(s, 1);
      s += __shfl_xor(s, 2);
      s += __shfl_xor(s, 4);
      s += __shfl_xor(s, 8);
      if (c16 == 0) atomicAdd(&s_sum1[m], s);
    }
  __syncthreads();  // B2: softmax denominators ready

  // t = relu(p - tau); row sum of t
#pragma unroll
  for (int mt = 0; mt < 2; ++mt)
#pragma unroll
    for (int r = 0; r < 4; ++r) {
      const int m = mt * 16 + q * 4 + r;
      const float isum = 1.f / s_sum1[m];
      float s = 0.f;
#pragma unroll
      for (int nt = 0; nt < 4; ++nt) {
        const float tv = fmaxf(acc[mt][nt][r] * isum - TAU, 0.f);
        acc[mt][nt][r] = tv;
        s += tv;
      }
      s += __shfl_xor(s, 1);
      s += __shfl_xor(s, 2);
      s += __shfl_xor(s, 4);
      s += __shfl_xor(s, 8);
      if (c16 == 0) atomicAdd(&s_sum2[m], s);
    }
  __syncthreads();  // B3: shrink sums ready

  // ---- normalize att in regs; emit the rare survivors to per-pixel LDS lists
  //      AND scatter them (scalar dword) into the pre-zeroed att_map.
#pragma unroll
  for (int mt = 0; mt < 2; ++mt) {
    float rs[4];
#pragma unroll
    for (int r = 0; r < 4; ++r)
      rs[r] = 1.f / fmaxf(s_sum2[mt * 16 + q * 4 + r], 1e-12f);
#pragma unroll
    for (int nt = 0; nt < 4; ++nt) {
      floatx4 a4 = acc[mt][nt];
      const unsigned n = wave * 64 + nt * 16 + c16;
#pragma unroll
      for (int r = 0; r < 4; ++r) {
        a4[r] *= rs[r];
        if (a4[r] > 0.f) {
          const int m = mt * 16 + q * 4 + r;
          const int idx = atomicAdd(&s_cnt[m], 1);
          if (idx < LCAP) {
            s_lslot[m][idx] = (unsigned short)n;
            s_lval[m][idx]  = a4[r];
          }
          attmap[((size_t)img * M_DIM + n) * HW + hw0 + m] = a4[r];
        }
      }
    }
  }
  BAR_LGKM();  // B4: lists ready — LDS-only sync; global stores keep draining

  // ---- sparse gather, fully predicated: out is pre-zeroed, so only pixel
  //      groups with at least one survivor need any loads/stores at all.
  const int px4 = (tid & 7) * 4;    // pixels px4..px4+3
  const int chg = tid >> 3;         // 0..63 -> channels [4*chg, 4*chg+4)
  int cn[4];
  int any = 0;
#pragma unroll
  for (int p = 0; p < 4; ++p) { cn[p] = min(s_cnt[px4 + p], LCAP); any += cn[p]; }
  if (any) {
    floatx4 f[4] = {{0.f,0.f,0.f,0.f},{0.f,0.f,0.f,0.f},{0.f,0.f,0.f,0.f},{0.f,0.f,0.f,0.f}};
#pragma unroll
    for (int p = 0; p < 4; ++p) {
      for (int j = 0; j < cn[p]; ++j) {
        const int slot  = s_lslot[px4 + p][j];
        const float v   = s_lval[px4 + p][j];
        const floatx4 r0 = *(const floatx4*)(mN32 + (size_t)slot * C_DIM + chg * 4);
        f[0][p] += v * r0[0]; f[1][p] += v * r0[1];
        f[2][p] += v * r0[2]; f[3][p] += v * r0[3];
      }
    }
#pragma unroll
    for (int c = 0; c < 4; ++c)
      *(floatx4*)(out + ((size_t)img * C_DIM + chg * 4 + c) * HW + hw0 + px4) = f[c];
  }
}

extern "C" void kernel_launch(void* const* d_in, const int* in_sizes, int n_in,
                              void* d_out, int out_size, void* d_ws, size_t ws_size,
                              hipStream_t stream) {
  (void)in_sizes; (void)n_in; (void)out_size; (void)ws_size;
  const float* x      = (const float*)d_in[0];
  const float* memory = (const float*)d_in[1];
  const float* w1     = (const float*)d_in[2];
  const float* b1     = (const float*)d_in[3];
  const float* w2     = (const float*)d_in[4];
  const float* b2     = (const float*)d_in[5];
  float* out    = (float*)d_out;
  float* attmap = out + (size_t)16 * C_DIM * HW;  // output first, att_map second

  _Float16* mN   = (_Float16*)d_ws;
  float*    mN32 = (float*)((char*)d_ws + (size_t)M_DIM * C_DIM * sizeof(_Float16));

  hipLaunchKernelGGL(prep_kernel, dim3(M_DIM), dim3(128), 0, stream,
                     memory, w1, b1, w2, b2, mN, mN32, out);
  hipLaunchKernelGGL(main_kernel, dim3(2048), dim3(512), 0, stream,
                     x, mN, mN32, out, attmap);
}

// Round 8
// 343.822 us; speedup vs baseline: 1.1444x; 1.0198x over previous
//
#include <hip/hip_runtime.h>

typedef _Float16 half8 __attribute__((ext_vector_type(8)));
typedef _Float16 half4v __attribute__((ext_vector_type(4)));
typedef float floatx4 __attribute__((ext_vector_type(4)));

#define C_DIM 256
#define M_DIM 512
#define HW 4096
#define TAU 0.0025f
#define LCAP 16

// Raw barrier: LDS-visibility only (skip the implicit vmcnt(0) drain of
// __syncthreads). Used where the post-barrier phase reads ONLY LDS, so
// in-flight global stores keep draining underneath (HK T4 pattern).
// sched_barrier(0) stops hipcc hoisting post-barrier ops above it (rule #18).
#define BAR_LGKM()                                          \
  do {                                                      \
    asm volatile("s_waitcnt lgkmcnt(0)" ::: "memory");      \
    __builtin_amdgcn_s_barrier();                           \
    __builtin_amdgcn_sched_barrier(0);                      \
  } while (0)

// ---------------- prep: fill(out+attmap) + memN MLP, fused (R0 structure) ----------
// R18: fill uses PLAIN (allocating) stores, NOT nontemporal. Measured contrast:
// R0 (plain, 134 MB) -> prep effectively ~0-5 us (stores ack at L2; dirty-line
// writeback drains under main's ~110 us execution). R17 (NT, 201 MB) -> prep ~40 us
// serialized at HBM write speed. Plain wins for PREP because main provides a long
// compute shadow after it; (NT remains right for stores issued at the END of the
// pipeline, where writeback would collide with the next poison fill - R3 lesson.)
// Fill covers BOTH out (67 MB) and att_map (134 MB): 192 float4/thread.
// MLP arithmetic/reduction order bit-identical to original (absmax==0.0).
__global__ __launch_bounds__(128) void prep_kernel(
    const float* __restrict__ memory, const float* __restrict__ w1,
    const float* __restrict__ b1, const float* __restrict__ w2,
    const float* __restrict__ b2,
    _Float16* __restrict__ mN, float* __restrict__ mN32,
    float* __restrict__ outbase)
{
  __shared__ float sm[256];
  __shared__ float sh[128];
  __shared__ float s_part[2];
  __shared__ float s_tot;
  const int r = blockIdx.x;   // 0..511
  const int t = threadIdx.x;  // 0..127

  // hoist MLP input loads: in flight during the fill below
  const float m0 = memory[r * C_DIM + t];
  const float m1 = memory[r * C_DIM + t + 128];
  const float bb1 = b1[t];

  // ---- out+attmap zero-fill: 512 blocks x 128 thr x 192 float4 = 201.3 MB,
  //      plain allocating stores (see header comment), coalesced 1 MB/iter.
  {
    const floatx4 z = {0.f, 0.f, 0.f, 0.f};
    floatx4* p4 = (floatx4*)outbase + (size_t)r * 128 + t;  // 65536 threads
#pragma unroll 4
    for (int k = 0; k < 192; ++k)
      p4[(size_t)k * 65536] = z;
  }

  sm[t]       = m0;
  sm[t + 128] = m1;
  __syncthreads();
  float acc = bb1;
#pragma unroll 8
  for (int c = 0; c < 256; ++c) acc = fmaf(sm[c], w1[c * 128 + t], acc);
  sh[t] = fmaxf(acc, 0.f);
  __syncthreads();
  float o0 = b2[t], o1 = b2[t + 128];
#pragma unroll 8
  for (int k = 0; k < 128; ++k) {
    float h = sh[k];
    o0 = fmaf(h, w2[k * 256 + t], o0);
    o1 = fmaf(h, w2[k * 256 + t + 128], o1);
  }
  o0 = fmaxf(o0, 0.f);
  o1 = fmaxf(o1, 0.f);
  float ss = o0 * o0 + o1 * o1;
#pragma unroll
  for (int off = 32; off >= 1; off >>= 1) ss += __shfl_down(ss, off);
  if ((t & 63) == 0) s_part[t >> 6] = ss;
  __syncthreads();
  if (t == 0) s_tot = s_part[0] + s_part[1];
  __syncthreads();
  const float inv = 1.f / fmaxf(sqrtf(s_tot), 1e-12f);
  const float v0 = o0 * inv, v1 = o1 * inv;
  mN[r * C_DIM + t]        = (_Float16)v0;
  mN[r * C_DIM + t + 128]  = (_Float16)v1;
  mN32[r * C_DIM + t]       = v0;
  mN32[r * C_DIM + t + 128] = v1;
}

#define MFMA16(a, b, c) __builtin_amdgcn_mfma_f32_16x16x32_f16(a, b, c, 0, 0, 0)

// ---------------- fused main kernel: 32 pixels per block, 2048 blocks ----------------
// R4/R14 main VERBATIM — the best-measured main (~112 us): 32-px tile, acc[2][4] =
// 32 AGPR, 20.5 KB LDS, 3 blocks/CU; outputs pre-zeroed in prep -> main scatters
// ONLY survivors (a4[r] > 0, ~1e-5 density) and the gather/out-store phase is
// predicated on per-pixel survivor counts (most blocks store nothing).
// R6 lesson baked in: NO cross-tile register prefetch (it spilled: 108 MB scratch).
__global__ __launch_bounds__(512, 6) void main_kernel(
    const float* __restrict__ x,
    const _Float16* __restrict__ mN,
    const float* __restrict__ mN32,
    float* __restrict__ out, float* __restrict__ attmap)
{
  __shared__ _Float16       Xh[32][264];       // 16896 B
  __shared__ unsigned short s_lslot[32][LCAP]; // 1024 B
  __shared__ float          s_lval[32][LCAP];  // 2048 B
  __shared__ int      s_cnt[32];
  __shared__ float    s_sumsq[32];
  __shared__ float    s_sum1[32];
  __shared__ float    s_sum2[32];               // total 20480 B

  const int tid  = threadIdx.x;
  const int wave = tid >> 6;     // 0..7
  const int lane = tid & 63;
  const int q    = lane >> 4;    // quad within wave
  const int c16  = lane & 15;
  const int g    = tid >> 3;     // 0..63: channel quad for phase A
  const int pxq  = tid & 7;      // pixel quad for phase A

  const int blk = blockIdx.x;          // 2048 blocks
  const int img = blk >> 7;            // 128 blocks per image
  const int hw0 = (blk & 127) * 32;
  const float* __restrict__ xb = x + (size_t)img * C_DIM * HW + hw0;

  if (tid < 32) {
    s_sumsq[tid] = 0.f; s_sum1[tid] = 0.f; s_sum2[tid] = 0.f; s_cnt[tid] = 0;
  }
  __syncthreads();  // B0

  // ---- Phase A: float4 loads (4 ch x 4 px per thread), fp16 pack, sumsq
  {
    floatx4 v[4];
#pragma unroll
    for (int i = 0; i < 4; ++i)
      v[i] = *(const floatx4*)(xb + (size_t)(4 * g + i) * HW + pxq * 4);
    float ps[4];
#pragma unroll
    for (int j = 0; j < 4; ++j) {
      const int p = pxq * 4 + j;
      half4v hv = {(_Float16)v[0][j], (_Float16)v[1][j], (_Float16)v[2][j], (_Float16)v[3][j]};
      *(half4v*)&Xh[p][4 * g] = hv;
      ps[j] = v[0][j] * v[0][j] + v[1][j] * v[1][j] + v[2][j] * v[2][j] + v[3][j] * v[3][j];
    }
#pragma unroll
    for (int off = 8; off < 64; off <<= 1)
#pragma unroll
      for (int j = 0; j < 4; ++j) ps[j] += __shfl_xor(ps[j], off);
    if ((lane >> 3) == 0) {
#pragma unroll
      for (int j = 0; j < 4; ++j) atomicAdd(&s_sumsq[4 * (lane & 7) + j], ps[j]);
    }
  }

  // B base pointers (kb offsets fold into the 13-bit imm: kb*32 halves = 64..448 B)
  const _Float16* bp[4];
#pragma unroll
  for (int nt = 0; nt < 4; ++nt)
    bp[nt] = mN + (size_t)(wave * 64 + nt * 16 + c16) * C_DIM + q * 8;

  __syncthreads();  // B1: Xh + sumsq ready

  // ---- Phase B: GEMM1  S[32][512] = Xh @ mN^T  (fp16 MFMA)
  floatx4 acc[2][4];
#pragma unroll
  for (int mt = 0; mt < 2; ++mt)
#pragma unroll
    for (int nt = 0; nt < 4; ++nt) {
      floatx4 z = {0.f, 0.f, 0.f, 0.f};
      acc[mt][nt] = z;
    }
#pragma unroll
  for (int kb = 0; kb < 8; ++kb) {
    half8 bv[4];
#pragma unroll
    for (int nt = 0; nt < 4; ++nt) bv[nt] = *(const half8*)(bp[nt] + kb * 32);
    const int k0 = kb * 32 + q * 8;
    half8 a0 = *(const half8*)&Xh[c16][k0];
    half8 a1 = *(const half8*)&Xh[16 + c16][k0];
#pragma unroll
    for (int nt = 0; nt < 4; ++nt) {
      acc[0][nt] = MFMA16(a0, bv[nt], acc[0][nt]);
      acc[1][nt] = MFMA16(a1, bv[nt], acc[1][nt]);
    }
  }

  // ---- Phase C: scale by 1/||x||, exp (cosines in [-1,1], no max shift needed)
  // C/D layout: value (m = mt*16 + q*4 + r, n = wave*64 + nt*16 + c16)
#pragma unroll
  for (int mt = 0; mt < 2; ++mt)
#pragma unroll
    for (int r = 0; r < 4; ++r) {
      const int m = mt * 16 + q * 4 + r;
      const float iv = 1.f / fmaxf(sqrtf(s_sumsq[m]), 1e-12f);
      float s = 0.f;
#pragma unroll
      for (int nt = 0; nt < 4; ++nt) {
        const float e = __expf(acc[mt][nt][r] * iv);
        acc[mt][nt][r] = e;
        s += e;
      }
      s += __shfl_xor(s, 1);
      s += __shfl_xor(s, 2);
      s += __shfl_xor(s, 4);
      s += __shfl_xor(s, 8);
      if (c16 == 0) atomicAdd(&s_sum1[m], s);
    }
  __syncthreads();  // B2: softmax denominators ready

  // t = relu(p - tau); row sum of t
#pragma unroll
  for (int mt = 0; mt < 2; ++mt)
#pragma unroll
    for (int r = 0; r < 4; ++r) {
      const int m = mt * 16 + q * 4 + r;
      const float isum = 1.f / s_sum1[m];
      float s = 0.f;
#pragma unroll
      for (int nt = 0; nt < 4; ++nt) {
        const float tv = fmaxf(acc[mt][nt][r] * isum - TAU, 0.f);
        acc[mt][nt][r] = tv;
        s += tv;
      }
      s += __shfl_xor(s, 1);
      s += __shfl_xor(s, 2);
      s += __shfl_xor(s, 4);
      s += __shfl_xor(s, 8);
      if (c16 == 0) atomicAdd(&s_sum2[m], s);
    }
  __syncthreads();  // B3: shrink sums ready

  // ---- normalize att in regs; emit the rare survivors to per-pixel LDS lists
  //      AND scatter them (scalar dword) into the pre-zeroed att_map.
#pragma unroll
  for (int mt = 0; mt < 2; ++mt) {
    float rs[4];
#pragma unroll
    for (int r = 0; r < 4; ++r)
      rs[r] = 1.f / fmaxf(s_sum2[mt * 16 + q * 4 + r], 1e-12f);
#pragma unroll
    for (int nt = 0; nt < 4; ++nt) {
      floatx4 a4 = acc[mt][nt];
      const unsigned n = wave * 64 + nt * 16 + c16;
#pragma unroll
      for (int r = 0; r < 4; ++r) {
        a4[r] *= rs[r];
        if (a4[r] > 0.f) {
          const int m = mt * 16 + q * 4 + r;
          const int idx = atomicAdd(&s_cnt[m], 1);
          if (idx < LCAP) {
            s_lslot[m][idx] = (unsigned short)n;
            s_lval[m][idx]  = a4[r];
          }
          attmap[((size_t)img * M_DIM + n) * HW + hw0 + m] = a4[r];
        }
      }
    }
  }
  BAR_LGKM();  // B4: lists ready — LDS-only sync; global stores keep draining

  // ---- sparse gather, fully predicated: out is pre-zeroed, so only pixel
  //      groups with at least one survivor need any loads/stores at all.
  const int px4 = (tid & 7) * 4;    // pixels px4..px4+3
  const int chg = tid >> 3;         // 0..63 -> channels [4*chg, 4*chg+4)
  int cn[4];
  int any = 0;
#pragma unroll
  for (int p = 0; p < 4; ++p) { cn[p] = min(s_cnt[px4 + p], LCAP); any += cn[p]; }
  if (any) {
    floatx4 f[4] = {{0.f,0.f,0.f,0.f},{0.f,0.f,0.f,0.f},{0.f,0.f,0.f,0.f},{0.f,0.f,0.f,0.f}};
#pragma unroll
    for (int p = 0; p < 4; ++p) {
      for (int j = 0; j < cn[p]; ++j) {
        const int slot  = s_lslot[px4 + p][j];
        const float v   = s_lval[px4 + p][j];
        const floatx4 r0 = *(const floatx4*)(mN32 + (size_t)slot * C_DIM + chg * 4);
        f[0][p] += v * r0[0]; f[1][p] += v * r0[1];
        f[2][p] += v * r0[2]; f[3][p] += v * r0[3];
      }
    }
#pragma unroll
    for (int c = 0; c < 4; ++c)
      *(floatx4*)(out + ((size_t)img * C_DIM + chg * 4 + c) * HW + hw0 + px4) = f[c];
  }
}

extern "C" void kernel_launch(void* const* d_in, const int* in_sizes, int n_in,
                              void* d_out, int out_size, void* d_ws, size_t ws_size,
                              hipStream_t stream) {
  (void)in_sizes; (void)n_in; (void)out_size; (void)ws_size;
  const float* x      = (const float*)d_in[0];
  const float* memory = (const float*)d_in[1];
  const float* w1     = (const float*)d_in[2];
  const float* b1     = (const float*)d_in[3];
  const float* w2     = (const float*)d_in[4];
  const float* b2     = (const float*)d_in[5];
  float* out    = (float*)d_out;
  float* attmap = out + (size_t)16 * C_DIM * HW;  // output first, att_map second

  _Float16* mN   = (_Float16*)d_ws;
  float*    mN32 = (float*)((char*)d_ws + (size_t)M_DIM * C_DIM * sizeof(_Float16));

  hipLaunchKernelGGL(prep_kernel, dim3(M_DIM), dim3(128), 0, stream,
                     memory, w1, b1, w2, b2, mN, mN32, out);
  hipLaunchKernelGGL(main_kernel, dim3(2048), dim3(512), 0, stream,
                     x, mN, mN32, out, attmap);
}